// Round 15
// baseline (283.624 us; speedup 1.0000x reference)
//
#include <hip/hip_runtime.h>

#define N_NODES 100000
#define N_EDGES 2500000
#define DIM 32
#define N_REL 6
#define N_BASES 4
#define N_SEG (N_NODES * N_REL)           // 600000 (dst,rel) segments
#define CB 196                             // coarse buckets: dst>>9
#define CNODES 512
#define CSEG (CNODES * N_REL)              // 3072 fine segments per coarse bucket
#define NBLK 256                           // partition blocks (1/CU)
#define SCAN_N (CB * NBLK)                 // 50176 = 1024 * 49
#define NITEM 49
#define GH_NODES 160                       // nodes per gemm_h block (100000 = 625*160)

// ---- pass 1: per-block bucket histogram -> cnt2[bucket*NBLK + block] ---------
__global__ __launch_bounds__(1024) void hist2_kernel(const int* __restrict__ dst,
                                                     int* __restrict__ cnt2) {
  __shared__ int h[CB];
  int t = threadIdx.x;
  for (int i = t; i < CB; i += 1024) h[i] = 0;
  __syncthreads();
  int per = (N_EDGES + NBLK - 1) / NBLK;
  int bstart = blockIdx.x * per;
  int bend = bstart + per; if (bend > N_EDGES) bend = N_EDGES;
  for (int e = bstart + t; e < bend; e += 1024)
    atomicAdd(&h[dst[e] >> 9], 1);
  __syncthreads();
  for (int i = t; i < CB; i += 1024)
    cnt2[i * NBLK + blockIdx.x] = h[i];
}

// ---- pass 2: exclusive scan of cnt2 (bucket-major) + bOffs -------------------
__global__ __launch_bounds__(1024) void scan2_kernel(int* __restrict__ cnt2,
                                                     int* __restrict__ bOffs) {
  __shared__ int ts[1024];
  int t = threadIdx.x;
  int base = t * NITEM;
  int loc[NITEM];
  int s = 0;
#pragma unroll
  for (int k = 0; k < NITEM; ++k) { loc[k] = s; s += cnt2[base + k]; }
  ts[t] = s;
  __syncthreads();
  for (int off = 1; off < 1024; off <<= 1) {
    int u = (t >= off) ? ts[t - off] : 0;
    __syncthreads();
    ts[t] += u;
    __syncthreads();
  }
  int excl = ts[t] - s;
#pragma unroll
  for (int k = 0; k < NITEM; ++k) {
    int idx = base + k;
    int v = excl + loc[k];
    cnt2[idx] = v;
    if ((idx & (NBLK - 1)) == 0) bOffs[idx / NBLK] = v;   // bucket boundary
  }
  if (t == 0) bOffs[CB] = N_EDGES;
}

// ---- pass 3: scatter into private (bucket,block) runs ------------------------
// payload: src(17b)<<12 | dst_low9<<3 | et(3b)
__global__ __launch_bounds__(1024) void scatter2_kernel(const int* __restrict__ src,
                                                        const int* __restrict__ dst,
                                                        const int* __restrict__ et,
                                                        const int* __restrict__ cnt2,
                                                        unsigned* __restrict__ packed) {
  __shared__ int sbase[CB];
  __shared__ int lcnt[CB];
  int t = threadIdx.x;
  for (int i = t; i < CB; i += 1024) {
    sbase[i] = cnt2[i * NBLK + blockIdx.x];
    lcnt[i] = 0;
  }
  __syncthreads();
  int per = (N_EDGES + NBLK - 1) / NBLK;
  int bstart = blockIdx.x * per;
  int bend = bstart + per; if (bend > N_EDGES) bend = N_EDGES;
  for (int e = bstart + t; e < bend; e += 1024) {
    int d = dst[e];
    int b = d >> 9;
    unsigned pl = ((unsigned)src[e] << 12) | ((unsigned)(d & 511) << 3) | (unsigned)et[e];
    int p = atomicAdd(&lcnt[b], 1);
    packed[sbase[b] + p] = pl;     // run private to this block -> clean lines
  }
}

// ------- phase B: per-coarse-bucket fine sort -> CSR + packed (row,cnt) -------
// eps[pos] = row(20b)<<12 | segcnt(12b); row = rel*N + src
__global__ __launch_bounds__(1024) void phaseB_kernel(const unsigned* __restrict__ packed,
                                                      const int* __restrict__ bOffs,
                                                      int* __restrict__ offs,
                                                      unsigned* __restrict__ eps) {
  __shared__ int scnt[CSEG];               // 12 KB
  __shared__ int sexcl[CSEG];              // 12 KB
  __shared__ unsigned short skeep[CSEG];   // 6 KB (segment counts)
  __shared__ int ssc[1024];                // 4 KB
  int b = blockIdx.x;
  int t = threadIdx.x;
  int beg = bOffs[b], end = bOffs[b + 1];
  for (int i = t; i < CSEG; i += 1024) scnt[i] = 0;
  __syncthreads();
  for (int i = beg + t; i < end; i += 1024) {
    unsigned pl = packed[i];
    int ls = (int)((pl >> 3) & 511u) * N_REL + (int)(pl & 7u);
    atomicAdd(&scnt[ls], 1);
  }
  __syncthreads();
  int b3 = t * 3;                // 3072 = 1024*3
  int a0 = scnt[b3], a1 = scnt[b3 + 1], a2 = scnt[b3 + 2];
  skeep[b3] = (unsigned short)a0;
  skeep[b3 + 1] = (unsigned short)a1;
  skeep[b3 + 2] = (unsigned short)a2;
  int s = a0 + a1 + a2;
  ssc[t] = s;
  __syncthreads();
  for (int off = 1; off < 1024; off <<= 1) {
    int u = (t >= off) ? ssc[t - off] : 0;
    __syncthreads();
    ssc[t] += u;
    __syncthreads();
  }
  int excl = ssc[t] - s;
  sexcl[b3] = excl; sexcl[b3 + 1] = excl + a0; sexcl[b3 + 2] = excl + a0 + a1;
#pragma unroll
  for (int k = 0; k < 3; ++k) {
    int ls = b3 + k;
    int gseg = b * CSEG + ls;
    if (gseg < N_SEG) offs[gseg] = beg + sexcl[ls];
  }
  if (b == 0 && t == 0) offs[N_SEG] = N_EDGES;
  __syncthreads();
  scnt[b3] = 0; scnt[b3 + 1] = 0; scnt[b3 + 2] = 0;
  __syncthreads();
  for (int i = beg + t; i < end; i += 1024) {
    unsigned pl = packed[i];
    int ls = (int)((pl >> 3) & 511u) * N_REL + (int)(pl & 7u);
    int p = atomicAdd(&scnt[ls], 1);
    int pos = beg + sexcl[ls] + p;
    unsigned sr = pl >> 12, rr = pl & 7u;
    unsigned cnt = (unsigned)skeep[ls]; if (cnt > 4095u) cnt = 4095u;
    eps[pos] = ((rr * (unsigned)N_NODES + sr) << 12) | cnt;
  }
}

// ------------- weights: Wf[r][i][o], r=0..5 basis-combined, r=6 root ----------
__global__ void weights_kernel(const float* __restrict__ comp1, const float* __restrict__ basis1,
                               const float* __restrict__ root1,
                               const float* __restrict__ comp2, const float* __restrict__ basis2,
                               const float* __restrict__ root2,
                               float* __restrict__ Wf1, float* __restrict__ Wf2) {
  int idx = blockIdx.x * blockDim.x + threadIdx.x;
  if (idx >= 2 * 7 * DIM * DIM) return;
  int layer = idx / (7 * DIM * DIM);
  int rem = idx - layer * (7 * DIM * DIM);
  int r = rem / (DIM * DIM);
  int io = rem - r * (DIM * DIM);        // i*32+o
  const float* comp  = layer ? comp2  : comp1;
  const float* basis = layer ? basis2 : basis1;
  const float* root  = layer ? root2  : root1;
  float val;
  if (r < 6) {
    val = 0.f;
#pragma unroll
    for (int bb = 0; bb < N_BASES; ++bb)
      val += comp[r * N_BASES + bb] * basis[bb * DIM * DIM + io];
  } else {
    val = root[io];
  }
  (layer ? Wf2 : Wf1)[rem] = val;
}

// ---- RNE float -> bf16 (bit trick, matches __float2bfloat16 for normals) -----
__device__ __forceinline__ unsigned short f2bf(float f) {
  unsigned u = __float_as_uint(f);
  unsigned rb = ((u >> 16) & 1u) + 0x7fffu;      // round-to-nearest-even
  return (unsigned short)((u + rb) >> 16);
}

// --- h precompute: stage x ONCE; 14 waves; wave wv -> plane wv>>1, half wv&1 --
// w[32] once per wave, constant indices -> registers (R11 rule); 28 waves/CU
__global__ __launch_bounds__(896) void gemm_h_kernel(const float* __restrict__ x,
                                                     const float* __restrict__ Wf,
                                                     unsigned short* __restrict__ h) {
  __shared__ float mst[GH_NODES * 36];   // padded stride 36 floats (9 float4)
  int n0 = blockIdx.x * GH_NODES;
  {
    const float4* x4 = (const float4*)(x + (size_t)n0 * 32);
    int t = threadIdx.x;                 // 1280 float4 over 896 threads
    *(float4*)&mst[(t >> 3) * 36 + (t & 7) * 4] = x4[t];
    if (t < 384) {
      int g = 896 + t;
      *(float4*)&mst[(g >> 3) * 36 + (g & 7) * 4] = x4[g];
    }
  }
  int lane = threadIdx.x & 63, wv = threadIdx.x >> 6;   // wv = 0..13
  int half = lane >> 5, l5 = lane & 31;
  int r = wv >> 1;                        // plane 0..6
  int nh = wv & 1;                        // node-half of the tile
  const float* Wr = Wf + r * 1024;
  float w[32];
#pragma unroll
  for (int i = 0; i < 32; ++i) w[i] = Wr[i * 32 + l5];   // once; L1/L2-hot
  __syncthreads();
  unsigned short* hr = h + (size_t)r * N_NODES * 32;
#pragma unroll 4
  for (int k = 0; k < 40; ++k) {
    int nl = nh * 80 + k * 2 + half;                     // 2 nodes per wave/iter
    const float4* mrow = (const float4*)&mst[nl * 36];
    float a0 = 0.f, a1 = 0.f, a2 = 0.f, a3 = 0.f;        // 4 independent chains
#pragma unroll
    for (int i4 = 0; i4 < 8; i4 += 2) {
      float4 p = mrow[i4];                               // LDS broadcast read
      float4 q = mrow[i4 + 1];
      a0 = fmaf(p.x, w[4 * i4 + 0], a0);
      a0 = fmaf(p.y, w[4 * i4 + 1], a0);
      a1 = fmaf(p.z, w[4 * i4 + 2], a1);
      a1 = fmaf(p.w, w[4 * i4 + 3], a1);
      a2 = fmaf(q.x, w[4 * i4 + 4], a2);
      a2 = fmaf(q.y, w[4 * i4 + 5], a2);
      a3 = fmaf(q.z, w[4 * i4 + 6], a3);
      a3 = fmaf(q.w, w[4 * i4 + 7], a3);
    }
    float acc = (a0 + a1) + (a2 + a3);
    hr[(size_t)(n0 + nl) * 32 + l5] = f2bf(acc);         // coalesced 2B store
  }
}

// ------------- consume: bf16 gather-sum, 4 edge-rows per gather instr ---------
// lane = q*16 + l4 (q=0..3): handles features {2*l4, 2*l4+1} of edge (e + q mod 4)
template <bool RELU>
__global__ __launch_bounds__(1024) void consume_kernel(const unsigned short* __restrict__ h,
                                                       const int* __restrict__ offs,
                                                       const unsigned* __restrict__ eps,
                                                       const float* __restrict__ bias,
                                                       float* __restrict__ y) {
  int wv = threadIdx.x >> 6, lane = threadIdx.x & 63;
  int l5 = lane & 31;                    // eps slot
  int q = lane >> 4;                     // quarter 0..3 (edge sub-index)
  int l4 = lane & 15;                    // feature pair index
  int n = blockIdx.x * 16 + wv;          // grid exact: 6250*16 = 100000
  int b0 = offs[n * N_REL], b6 = offs[n * N_REL + 6];
  unsigned F4 = (unsigned)(l4 << 2);     // byte offset of feature pair in 64B row
  const char* hb = (const char*)h;
  float acc0 = 0.f, acc1 = 0.f;
  for (int chunk = b0; chunk < b6; chunk += 32) {
    int myp = chunk + l5;
    int cl = (myp < b6) ? myp : (b6 - 1);
    unsigned ep = eps[cl];               // one 4B coalesced load per 32 edges
    unsigned en = (ep >> 12) << 6;       // row byte offset (bf16 row = 64B)
    float sc = (myp < b6) ? 1.f / (float)(ep & 4095u) : 0.f;   // exact 1/cnt
#pragma unroll
    for (int e = 0; e < 32; e += 8) {
      // 2 gather instrs cover 8 edges (4 rows x 16 lanes each)
      unsigned q0 = __shfl(en, e + 0 + q, 32);      // my edge's row offset
      unsigned q1 = __shfl(en, e + 4 + q, 32);
      float s0 = __shfl(sc, e + 0 + q, 32);
      float s1 = __shfl(sc, e + 4 + q, 32);
      unsigned v0 = *(const unsigned*)(hb + (q0 | F4));   // 2 bf16 features
      unsigned v1 = *(const unsigned*)(hb + (q1 | F4));
      acc0 = fmaf(s0, __uint_as_float(v0 << 16), acc0);           // even feat
      acc1 = fmaf(s0, __uint_as_float(v0 & 0xffff0000u), acc1);   // odd feat
      acc0 = fmaf(s1, __uint_as_float(v1 << 16), acc0);
      acc1 = fmaf(s1, __uint_as_float(v1 & 0xffff0000u), acc1);
    }
  }
  // combine quarters (each quarter summed a different residue class of edges)
  acc0 += __shfl_xor(acc0, 16);
  acc0 += __shfl_xor(acc0, 32);
  acc1 += __shfl_xor(acc1, 16);
  acc1 += __shfl_xor(acc1, 32);
  // root row (bf16) + bias
  unsigned rv = *(const unsigned*)(hb + ((((size_t)6 * N_NODES + n) << 6)) + F4);
  float r0 = acc0 + __uint_as_float(rv << 16) + bias[2 * l4];
  float r1 = acc1 + __uint_as_float(rv & 0xffff0000u) + bias[2 * l4 + 1];
  if (RELU) { r0 = fmaxf(r0, 0.f); r1 = fmaxf(r1, 0.f); }
  if (lane < 16) {
    float2 st; st.x = r0; st.y = r1;
    *(float2*)(y + (size_t)n * 32 + 2 * l4) = st;
  }
}

extern "C" void kernel_launch(void* const* d_in, const int* in_sizes, int n_in,
                              void* d_out, int out_size, void* d_ws, size_t ws_size,
                              hipStream_t stream) {
  const float* embedding = (const float*)d_in[0];
  const int*   ei        = (const int*)d_in[1];     // [2, E]: src row, dst row
  const int*   et        = (const int*)d_in[2];
  const float* comp1  = (const float*)d_in[3];
  const float* basis1 = (const float*)d_in[4];
  const float* root1  = (const float*)d_in[5];
  const float* bias1  = (const float*)d_in[6];
  const float* comp2  = (const float*)d_in[7];
  const float* basis2 = (const float*)d_in[8];
  const float* root2  = (const float*)d_in[9];
  const float* bias2  = (const float*)d_in[10];
  float* out = (float*)d_out;

  const int* src = ei;
  const int* dst = ei + N_EDGES;

  float* ws = (float*)d_ws;
  size_t o = 0;
  float* Wf1 = ws + o; o += 7 * DIM * DIM;
  float* Wf2 = ws + o; o += 7 * DIM * DIM;
  float* x1  = ws + o; o += (size_t)N_NODES * DIM;
  unsigned short* h = (unsigned short*)(ws + o);
  o += (size_t)7 * N_NODES * DIM / 2 + 16;               // bf16 h: 44.8 MB
  int* offs       = (int*)(ws + o); o += N_SEG + 1;
  unsigned* eps   = (unsigned*)(ws + o); o += N_EDGES;   // packed row|cnt
  int* cnt2       = (int*)(ws + o); o += SCAN_N;
  int* bOffs      = (int*)(ws + o); o += CB + 1;
  unsigned* packed = (unsigned*)h;       // alias: dead before gemm_h writes h

  hist2_kernel<<<NBLK, 1024, 0, stream>>>(dst, cnt2);
  scan2_kernel<<<1, 1024, 0, stream>>>(cnt2, bOffs);
  scatter2_kernel<<<NBLK, 1024, 0, stream>>>(src, dst, et, cnt2, packed);
  phaseB_kernel<<<CB, 1024, 0, stream>>>(packed, bOffs, offs, eps);
  weights_kernel<<<(2 * 7 * DIM * DIM + 255) / 256, 256, 0, stream>>>(
      comp1, basis1, root1, comp2, basis2, root2, Wf1, Wf2);

  // layer 1
  gemm_h_kernel<<<N_NODES / GH_NODES, 896, 0, stream>>>(embedding, Wf1, h);
  consume_kernel<true><<<N_NODES / 16, 1024, 0, stream>>>(h, offs, eps, bias1, x1);
  // layer 2
  gemm_h_kernel<<<N_NODES / GH_NODES, 896, 0, stream>>>(x1, Wf2, h);
  consume_kernel<false><<<N_NODES / 16, 1024, 0, stream>>>(h, offs, eps, bias2, out);
}

// Round 16
// 246.980 us; speedup vs baseline: 1.1484x; 1.1484x over previous
//
#include <hip/hip_runtime.h>

#define N_NODES 100000
#define N_EDGES 2500000
#define DIM 32
#define N_REL 6
#define N_BASES 4
#define N_SEG (N_NODES * N_REL)           // 600000 (dst,rel) segments
#define CB 196                             // coarse buckets: dst>>9
#define CNODES 512
#define CSEG (CNODES * N_REL)              // 3072 fine segments per coarse bucket
#define NBLK 256                           // partition blocks (1/CU)
#define SCAN_N (CB * NBLK)                 // 50176 = 1024 * 49
#define NITEM 49
#define GH_NODES 160                       // nodes per gemm_h block (100000 = 625*160)

// ---- pass 1: per-block bucket histogram -> cnt2[bucket*NBLK + block] ---------
__global__ __launch_bounds__(1024) void hist2_kernel(const int* __restrict__ dst,
                                                     int* __restrict__ cnt2) {
  __shared__ int h[CB];
  int t = threadIdx.x;
  for (int i = t; i < CB; i += 1024) h[i] = 0;
  __syncthreads();
  int per = (N_EDGES + NBLK - 1) / NBLK;
  int bstart = blockIdx.x * per;
  int bend = bstart + per; if (bend > N_EDGES) bend = N_EDGES;
  for (int e = bstart + t; e < bend; e += 1024)
    atomicAdd(&h[dst[e] >> 9], 1);
  __syncthreads();
  for (int i = t; i < CB; i += 1024)
    cnt2[i * NBLK + blockIdx.x] = h[i];
}

// ---- pass 2: exclusive scan of cnt2 (bucket-major) + bOffs -------------------
__global__ __launch_bounds__(1024) void scan2_kernel(int* __restrict__ cnt2,
                                                     int* __restrict__ bOffs) {
  __shared__ int ts[1024];
  int t = threadIdx.x;
  int base = t * NITEM;
  int loc[NITEM];
  int s = 0;
#pragma unroll
  for (int k = 0; k < NITEM; ++k) { loc[k] = s; s += cnt2[base + k]; }
  ts[t] = s;
  __syncthreads();
  for (int off = 1; off < 1024; off <<= 1) {
    int u = (t >= off) ? ts[t - off] : 0;
    __syncthreads();
    ts[t] += u;
    __syncthreads();
  }
  int excl = ts[t] - s;
#pragma unroll
  for (int k = 0; k < NITEM; ++k) {
    int idx = base + k;
    int v = excl + loc[k];
    cnt2[idx] = v;
    if ((idx & (NBLK - 1)) == 0) bOffs[idx / NBLK] = v;   // bucket boundary
  }
  if (t == 0) bOffs[CB] = N_EDGES;
}

// ---- pass 3: scatter into private (bucket,block) runs ------------------------
// payload: src(17b)<<12 | dst_low9<<3 | et(3b)
__global__ __launch_bounds__(1024) void scatter2_kernel(const int* __restrict__ src,
                                                        const int* __restrict__ dst,
                                                        const int* __restrict__ et,
                                                        const int* __restrict__ cnt2,
                                                        unsigned* __restrict__ packed) {
  __shared__ int sbase[CB];
  __shared__ int lcnt[CB];
  int t = threadIdx.x;
  for (int i = t; i < CB; i += 1024) {
    sbase[i] = cnt2[i * NBLK + blockIdx.x];
    lcnt[i] = 0;
  }
  __syncthreads();
  int per = (N_EDGES + NBLK - 1) / NBLK;
  int bstart = blockIdx.x * per;
  int bend = bstart + per; if (bend > N_EDGES) bend = N_EDGES;
  for (int e = bstart + t; e < bend; e += 1024) {
    int d = dst[e];
    int b = d >> 9;
    unsigned pl = ((unsigned)src[e] << 12) | ((unsigned)(d & 511) << 3) | (unsigned)et[e];
    int p = atomicAdd(&lcnt[b], 1);
    packed[sbase[b] + p] = pl;     // run private to this block -> clean lines
  }
}

// ------- phase B: per-coarse-bucket fine sort -> CSR + packed (row,cnt) -------
// eps[pos] = row(20b)<<12 | segcnt(12b); row = rel*N + src
__global__ __launch_bounds__(1024) void phaseB_kernel(const unsigned* __restrict__ packed,
                                                      const int* __restrict__ bOffs,
                                                      int* __restrict__ offs,
                                                      unsigned* __restrict__ eps) {
  __shared__ int scnt[CSEG];               // 12 KB
  __shared__ int sexcl[CSEG];              // 12 KB
  __shared__ unsigned short skeep[CSEG];   // 6 KB (segment counts)
  __shared__ int ssc[1024];                // 4 KB
  int b = blockIdx.x;
  int t = threadIdx.x;
  int beg = bOffs[b], end = bOffs[b + 1];
  for (int i = t; i < CSEG; i += 1024) scnt[i] = 0;
  __syncthreads();
  for (int i = beg + t; i < end; i += 1024) {
    unsigned pl = packed[i];
    int ls = (int)((pl >> 3) & 511u) * N_REL + (int)(pl & 7u);
    atomicAdd(&scnt[ls], 1);
  }
  __syncthreads();
  int b3 = t * 3;                // 3072 = 1024*3
  int a0 = scnt[b3], a1 = scnt[b3 + 1], a2 = scnt[b3 + 2];
  skeep[b3] = (unsigned short)a0;
  skeep[b3 + 1] = (unsigned short)a1;
  skeep[b3 + 2] = (unsigned short)a2;
  int s = a0 + a1 + a2;
  ssc[t] = s;
  __syncthreads();
  for (int off = 1; off < 1024; off <<= 1) {
    int u = (t >= off) ? ssc[t - off] : 0;
    __syncthreads();
    ssc[t] += u;
    __syncthreads();
  }
  int excl = ssc[t] - s;
  sexcl[b3] = excl; sexcl[b3 + 1] = excl + a0; sexcl[b3 + 2] = excl + a0 + a1;
#pragma unroll
  for (int k = 0; k < 3; ++k) {
    int ls = b3 + k;
    int gseg = b * CSEG + ls;
    if (gseg < N_SEG) offs[gseg] = beg + sexcl[ls];
  }
  if (b == 0 && t == 0) offs[N_SEG] = N_EDGES;
  __syncthreads();
  scnt[b3] = 0; scnt[b3 + 1] = 0; scnt[b3 + 2] = 0;
  __syncthreads();
  for (int i = beg + t; i < end; i += 1024) {
    unsigned pl = packed[i];
    int ls = (int)((pl >> 3) & 511u) * N_REL + (int)(pl & 7u);
    int p = atomicAdd(&scnt[ls], 1);
    int pos = beg + sexcl[ls] + p;
    unsigned sr = pl >> 12, rr = pl & 7u;
    unsigned cnt = (unsigned)skeep[ls]; if (cnt > 4095u) cnt = 4095u;
    eps[pos] = ((rr * (unsigned)N_NODES + sr) << 12) | cnt;
  }
}

// ------------- weights: Wf[r][i][o], r=0..5 basis-combined, r=6 root ----------
__global__ void weights_kernel(const float* __restrict__ comp1, const float* __restrict__ basis1,
                               const float* __restrict__ root1,
                               const float* __restrict__ comp2, const float* __restrict__ basis2,
                               const float* __restrict__ root2,
                               float* __restrict__ Wf1, float* __restrict__ Wf2) {
  int idx = blockIdx.x * blockDim.x + threadIdx.x;
  if (idx >= 2 * 7 * DIM * DIM) return;
  int layer = idx / (7 * DIM * DIM);
  int rem = idx - layer * (7 * DIM * DIM);
  int r = rem / (DIM * DIM);
  int io = rem - r * (DIM * DIM);        // i*32+o
  const float* comp  = layer ? comp2  : comp1;
  const float* basis = layer ? basis2 : basis1;
  const float* root  = layer ? root2  : root1;
  float val;
  if (r < 6) {
    val = 0.f;
#pragma unroll
    for (int bb = 0; bb < N_BASES; ++bb)
      val += comp[r * N_BASES + bb] * basis[bb * DIM * DIM + io];
  } else {
    val = root[io];
  }
  (layer ? Wf2 : Wf1)[rem] = val;
}

// ---- RNE float -> bf16 (bit trick, matches __float2bfloat16 for normals) -----
__device__ __forceinline__ unsigned short f2bf(float f) {
  unsigned u = __float_as_uint(f);
  unsigned rb = ((u >> 16) & 1u) + 0x7fffu;      // round-to-nearest-even
  return (unsigned short)((u + rb) >> 16);
}

// --- h precompute (R14 shape, 1-D grid): bid -> (tile=bid/7, r=bid%7) ---------
// Adjacent blocks share the same x tile -> L3/L2 temporal locality for re-reads
__global__ __launch_bounds__(1024) void gemm_h_kernel(const float* __restrict__ x,
                                                      const float* __restrict__ Wf,
                                                      unsigned short* __restrict__ h) {
  __shared__ float mst[GH_NODES * 36];   // padded stride 36 floats (9 float4)
  int bid = blockIdx.x;
  int r = bid % 7;                       // plane
  int n0 = (bid / 7) * GH_NODES;         // tile
  {
    const float4* x4 = (const float4*)(x + (size_t)n0 * 32);
    int t = threadIdx.x;                 // 1280 float4 in 2 rounds
    int row = t >> 3, col = t & 7;
    *(float4*)&mst[row * 36 + col * 4] = x4[t];
    if (t < 256) {
      int g = 1024 + t;
      *(float4*)&mst[(g >> 3) * 36 + (g & 7) * 4] = x4[g];
    }
  }
  int lane = threadIdx.x & 63, wv = threadIdx.x >> 6;
  int half = lane >> 5, l5 = lane & 31;
  const float* Wr = Wf + r * 1024;
  float w[32];
#pragma unroll
  for (int i = 0; i < 32; ++i) w[i] = Wr[i * 32 + l5];   // once; L2-hot broadcast
  __syncthreads();
  unsigned short* hr = h + (size_t)r * N_NODES * 32;
#pragma unroll
  for (int k = 0; k < 5; ++k) {
    int nl = wv * 10 + k * 2 + half;                      // 2 nodes per wave
    const float4* mrow = (const float4*)&mst[nl * 36];
    // 4 independent FMA chains (8 deep each) -> no serial-dep stall
    float a0 = 0.f, a1 = 0.f, a2 = 0.f, a3 = 0.f;
#pragma unroll
    for (int i4 = 0; i4 < 8; i4 += 2) {
      float4 p = mrow[i4];                                // LDS broadcast read
      float4 q = mrow[i4 + 1];
      a0 = fmaf(p.x, w[4 * i4 + 0], a0);
      a0 = fmaf(p.y, w[4 * i4 + 1], a0);
      a1 = fmaf(p.z, w[4 * i4 + 2], a1);
      a1 = fmaf(p.w, w[4 * i4 + 3], a1);
      a2 = fmaf(q.x, w[4 * i4 + 4], a2);
      a2 = fmaf(q.y, w[4 * i4 + 5], a2);
      a3 = fmaf(q.z, w[4 * i4 + 6], a3);
      a3 = fmaf(q.w, w[4 * i4 + 7], a3);
    }
    float acc = (a0 + a1) + (a2 + a3);
    hr[(size_t)(n0 + nl) * 32 + l5] = f2bf(acc);          // coalesced 2B store
  }
}

// ------------- consume: bf16 gather-sum, 4 edge-rows per gather instr ---------
// lane = q*16 + l4 (q=0..3): handles features {2*l4, 2*l4+1} of edge (e + q mod 4)
template <bool RELU>
__global__ __launch_bounds__(1024) void consume_kernel(const unsigned short* __restrict__ h,
                                                       const int* __restrict__ offs,
                                                       const unsigned* __restrict__ eps,
                                                       const float* __restrict__ bias,
                                                       float* __restrict__ y) {
  int wv = threadIdx.x >> 6, lane = threadIdx.x & 63;
  int l5 = lane & 31;                    // eps slot
  int q = lane >> 4;                     // quarter 0..3 (edge sub-index)
  int l4 = lane & 15;                    // feature pair index
  int n = blockIdx.x * 16 + wv;          // grid exact: 6250*16 = 100000
  int b0 = offs[n * N_REL], b6 = offs[n * N_REL + 6];
  unsigned F4 = (unsigned)(l4 << 2);     // byte offset of feature pair in 64B row
  const char* hb = (const char*)h;
  float acc0 = 0.f, acc1 = 0.f;
  for (int chunk = b0; chunk < b6; chunk += 32) {
    int myp = chunk + l5;
    int cl = (myp < b6) ? myp : (b6 - 1);
    unsigned ep = eps[cl];               // one 4B coalesced load per 32 edges
    unsigned en = (ep >> 12) << 6;       // row byte offset (bf16 row = 64B)
    float sc = (myp < b6) ? 1.f / (float)(ep & 4095u) : 0.f;   // exact 1/cnt
#pragma unroll
    for (int e = 0; e < 32; e += 8) {
      // 2 gather instrs cover 8 edges (4 rows x 16 lanes each)
      unsigned q0 = __shfl(en, e + 0 + q, 32);      // my edge's row offset
      unsigned q1 = __shfl(en, e + 4 + q, 32);
      float s0 = __shfl(sc, e + 0 + q, 32);
      float s1 = __shfl(sc, e + 4 + q, 32);
      unsigned v0 = *(const unsigned*)(hb + (q0 | F4));   // 2 bf16 features
      unsigned v1 = *(const unsigned*)(hb + (q1 | F4));
      acc0 = fmaf(s0, __uint_as_float(v0 << 16), acc0);           // even feat
      acc1 = fmaf(s0, __uint_as_float(v0 & 0xffff0000u), acc1);   // odd feat
      acc0 = fmaf(s1, __uint_as_float(v1 << 16), acc0);
      acc1 = fmaf(s1, __uint_as_float(v1 & 0xffff0000u), acc1);
    }
  }
  // combine quarters (each quarter summed a different residue class of edges)
  acc0 += __shfl_xor(acc0, 16);
  acc0 += __shfl_xor(acc0, 32);
  acc1 += __shfl_xor(acc1, 16);
  acc1 += __shfl_xor(acc1, 32);
  // root row (bf16) + bias
  unsigned rv = *(const unsigned*)(hb + ((((size_t)6 * N_NODES + n) << 6)) + F4);
  float r0 = acc0 + __uint_as_float(rv << 16) + bias[2 * l4];
  float r1 = acc1 + __uint_as_float(rv & 0xffff0000u) + bias[2 * l4 + 1];
  if (RELU) { r0 = fmaxf(r0, 0.f); r1 = fmaxf(r1, 0.f); }
  if (lane < 16) {
    float2 st; st.x = r0; st.y = r1;
    *(float2*)(y + (size_t)n * 32 + 2 * l4) = st;
  }
}

extern "C" void kernel_launch(void* const* d_in, const int* in_sizes, int n_in,
                              void* d_out, int out_size, void* d_ws, size_t ws_size,
                              hipStream_t stream) {
  const float* embedding = (const float*)d_in[0];
  const int*   ei        = (const int*)d_in[1];     // [2, E]: src row, dst row
  const int*   et        = (const int*)d_in[2];
  const float* comp1  = (const float*)d_in[3];
  const float* basis1 = (const float*)d_in[4];
  const float* root1  = (const float*)d_in[5];
  const float* bias1  = (const float*)d_in[6];
  const float* comp2  = (const float*)d_in[7];
  const float* basis2 = (const float*)d_in[8];
  const float* root2  = (const float*)d_in[9];
  const float* bias2  = (const float*)d_in[10];
  float* out = (float*)d_out;

  const int* src = ei;
  const int* dst = ei + N_EDGES;

  float* ws = (float*)d_ws;
  size_t o = 0;
  float* Wf1 = ws + o; o += 7 * DIM * DIM;
  float* Wf2 = ws + o; o += 7 * DIM * DIM;
  float* x1  = ws + o; o += (size_t)N_NODES * DIM;
  unsigned short* h = (unsigned short*)(ws + o);
  o += (size_t)7 * N_NODES * DIM / 2 + 16;               // bf16 h: 44.8 MB
  int* offs       = (int*)(ws + o); o += N_SEG + 1;
  unsigned* eps   = (unsigned*)(ws + o); o += N_EDGES;   // packed row|cnt
  int* cnt2       = (int*)(ws + o); o += SCAN_N;
  int* bOffs      = (int*)(ws + o); o += CB + 1;
  unsigned* packed = (unsigned*)h;       // alias: dead before gemm_h writes h

  hist2_kernel<<<NBLK, 1024, 0, stream>>>(dst, cnt2);
  scan2_kernel<<<1, 1024, 0, stream>>>(cnt2, bOffs);
  scatter2_kernel<<<NBLK, 1024, 0, stream>>>(src, dst, et, cnt2, packed);
  phaseB_kernel<<<CB, 1024, 0, stream>>>(packed, bOffs, offs, eps);
  weights_kernel<<<(2 * 7 * DIM * DIM + 255) / 256, 256, 0, stream>>>(
      comp1, basis1, root1, comp2, basis2, root2, Wf1, Wf2);

  // layer 1
  gemm_h_kernel<<<7 * (N_NODES / GH_NODES), 1024, 0, stream>>>(embedding, Wf1, h);
  consume_kernel<true><<<N_NODES / 16, 1024, 0, stream>>>(h, offs, eps, bias1, x1);
  // layer 2
  gemm_h_kernel<<<7 * (N_NODES / GH_NODES), 1024, 0, stream>>>(x1, Wf2, h);
  consume_kernel<false><<<N_NODES / 16, 1024, 0, stream>>>(h, offs, eps, bias2, out);
}

// Round 17
// 242.888 us; speedup vs baseline: 1.1677x; 1.0168x over previous
//
#include <hip/hip_runtime.h>

#define N_NODES 100000
#define N_EDGES 2500000
#define DIM 32
#define N_REL 6
#define N_BASES 4
#define N_SEG (N_NODES * N_REL)           // 600000 (dst,rel) segments
#define CB 196                             // coarse buckets: dst>>9
#define CNODES 512
#define CSEG (CNODES * N_REL)              // 3072 fine segments per coarse bucket
#define NBLK 256                           // partition blocks (1/CU)
#define SCAN_N (CB * NBLK)                 // 50176 = 1024 * 49
#define NITEM 49
#define GH_NODES 160                       // nodes per gemm_h block (100000 = 625*160)

// ---- pass 1: per-block bucket histogram -> cnt2[bucket*NBLK + block] ---------
__global__ __launch_bounds__(1024) void hist2_kernel(const int* __restrict__ dst,
                                                     int* __restrict__ cnt2) {
  __shared__ int h[CB];
  int t = threadIdx.x;
  for (int i = t; i < CB; i += 1024) h[i] = 0;
  __syncthreads();
  int per = (N_EDGES + NBLK - 1) / NBLK;
  int bstart = blockIdx.x * per;
  int bend = bstart + per; if (bend > N_EDGES) bend = N_EDGES;
  for (int e = bstart + t; e < bend; e += 1024)
    atomicAdd(&h[dst[e] >> 9], 1);
  __syncthreads();
  for (int i = t; i < CB; i += 1024)
    cnt2[i * NBLK + blockIdx.x] = h[i];
}

// ---- pass 2: exclusive scan of cnt2 (bucket-major) + bOffs -------------------
__global__ __launch_bounds__(1024) void scan2_kernel(int* __restrict__ cnt2,
                                                     int* __restrict__ bOffs) {
  __shared__ int ts[1024];
  int t = threadIdx.x;
  int base = t * NITEM;
  int loc[NITEM];
  int s = 0;
#pragma unroll
  for (int k = 0; k < NITEM; ++k) { loc[k] = s; s += cnt2[base + k]; }
  ts[t] = s;
  __syncthreads();
  for (int off = 1; off < 1024; off <<= 1) {
    int u = (t >= off) ? ts[t - off] : 0;
    __syncthreads();
    ts[t] += u;
    __syncthreads();
  }
  int excl = ts[t] - s;
#pragma unroll
  for (int k = 0; k < NITEM; ++k) {
    int idx = base + k;
    int v = excl + loc[k];
    cnt2[idx] = v;
    if ((idx & (NBLK - 1)) == 0) bOffs[idx / NBLK] = v;   // bucket boundary
  }
  if (t == 0) bOffs[CB] = N_EDGES;
}

// ---- pass 3: scatter into private (bucket,block) runs ------------------------
// payload: src(17b)<<12 | dst_low9<<3 | et(3b)
__global__ __launch_bounds__(1024) void scatter2_kernel(const int* __restrict__ src,
                                                        const int* __restrict__ dst,
                                                        const int* __restrict__ et,
                                                        const int* __restrict__ cnt2,
                                                        unsigned* __restrict__ packed) {
  __shared__ int sbase[CB];
  __shared__ int lcnt[CB];
  int t = threadIdx.x;
  for (int i = t; i < CB; i += 1024) {
    sbase[i] = cnt2[i * NBLK + blockIdx.x];
    lcnt[i] = 0;
  }
  __syncthreads();
  int per = (N_EDGES + NBLK - 1) / NBLK;
  int bstart = blockIdx.x * per;
  int bend = bstart + per; if (bend > N_EDGES) bend = N_EDGES;
  for (int e = bstart + t; e < bend; e += 1024) {
    int d = dst[e];
    int b = d >> 9;
    unsigned pl = ((unsigned)src[e] << 12) | ((unsigned)(d & 511) << 3) | (unsigned)et[e];
    int p = atomicAdd(&lcnt[b], 1);
    packed[sbase[b] + p] = pl;     // run private to this block -> clean lines
  }
}

// ------- phase B: per-coarse-bucket fine sort -> CSR + packed (row,cnt) -------
// eps[pos] = row(20b)<<12 | segcnt(12b); row = rel*N + src
__global__ __launch_bounds__(1024) void phaseB_kernel(const unsigned* __restrict__ packed,
                                                      const int* __restrict__ bOffs,
                                                      int* __restrict__ offs,
                                                      unsigned* __restrict__ eps) {
  __shared__ int scnt[CSEG];               // 12 KB
  __shared__ int sexcl[CSEG];              // 12 KB
  __shared__ unsigned short skeep[CSEG];   // 6 KB (segment counts)
  __shared__ int ssc[1024];                // 4 KB
  int b = blockIdx.x;
  int t = threadIdx.x;
  int beg = bOffs[b], end = bOffs[b + 1];
  for (int i = t; i < CSEG; i += 1024) scnt[i] = 0;
  __syncthreads();
  for (int i = beg + t; i < end; i += 1024) {
    unsigned pl = packed[i];
    int ls = (int)((pl >> 3) & 511u) * N_REL + (int)(pl & 7u);
    atomicAdd(&scnt[ls], 1);
  }
  __syncthreads();
  int b3 = t * 3;                // 3072 = 1024*3
  int a0 = scnt[b3], a1 = scnt[b3 + 1], a2 = scnt[b3 + 2];
  skeep[b3] = (unsigned short)a0;
  skeep[b3 + 1] = (unsigned short)a1;
  skeep[b3 + 2] = (unsigned short)a2;
  int s = a0 + a1 + a2;
  ssc[t] = s;
  __syncthreads();
  for (int off = 1; off < 1024; off <<= 1) {
    int u = (t >= off) ? ssc[t - off] : 0;
    __syncthreads();
    ssc[t] += u;
    __syncthreads();
  }
  int excl = ssc[t] - s;
  sexcl[b3] = excl; sexcl[b3 + 1] = excl + a0; sexcl[b3 + 2] = excl + a0 + a1;
#pragma unroll
  for (int k = 0; k < 3; ++k) {
    int ls = b3 + k;
    int gseg = b * CSEG + ls;
    if (gseg < N_SEG) offs[gseg] = beg + sexcl[ls];
  }
  if (b == 0 && t == 0) offs[N_SEG] = N_EDGES;
  __syncthreads();
  scnt[b3] = 0; scnt[b3 + 1] = 0; scnt[b3 + 2] = 0;
  __syncthreads();
  for (int i = beg + t; i < end; i += 1024) {
    unsigned pl = packed[i];
    int ls = (int)((pl >> 3) & 511u) * N_REL + (int)(pl & 7u);
    int p = atomicAdd(&scnt[ls], 1);
    int pos = beg + sexcl[ls] + p;
    unsigned sr = pl >> 12, rr = pl & 7u;
    unsigned cnt = (unsigned)skeep[ls]; if (cnt > 4095u) cnt = 4095u;
    eps[pos] = ((rr * (unsigned)N_NODES + sr) << 12) | cnt;
  }
}

// ------------- weights: Wf[r][i][o], r=0..5 basis-combined, r=6 root ----------
__global__ void weights_kernel(const float* __restrict__ comp1, const float* __restrict__ basis1,
                               const float* __restrict__ root1,
                               const float* __restrict__ comp2, const float* __restrict__ basis2,
                               const float* __restrict__ root2,
                               float* __restrict__ Wf1, float* __restrict__ Wf2) {
  int idx = blockIdx.x * blockDim.x + threadIdx.x;
  if (idx >= 2 * 7 * DIM * DIM) return;
  int layer = idx / (7 * DIM * DIM);
  int rem = idx - layer * (7 * DIM * DIM);
  int r = rem / (DIM * DIM);
  int io = rem - r * (DIM * DIM);        // i*32+o
  const float* comp  = layer ? comp2  : comp1;
  const float* basis = layer ? basis2 : basis1;
  const float* root  = layer ? root2  : root1;
  float val;
  if (r < 6) {
    val = 0.f;
#pragma unroll
    for (int bb = 0; bb < N_BASES; ++bb)
      val += comp[r * N_BASES + bb] * basis[bb * DIM * DIM + io];
  } else {
    val = root[io];
  }
  (layer ? Wf2 : Wf1)[rem] = val;
}

// ---- RNE float -> bf16 (bit trick, matches __float2bfloat16 for normals) -----
__device__ __forceinline__ unsigned short f2bf(float f) {
  unsigned u = __float_as_uint(f);
  unsigned rb = ((u >> 16) & 1u) + 0x7fffu;      // round-to-nearest-even
  return (unsigned short)((u + rb) >> 16);
}

// --- h precompute (R14 shape, 1-D grid): bid -> (tile=bid/7, r=bid%7) ---------
__global__ __launch_bounds__(1024) void gemm_h_kernel(const float* __restrict__ x,
                                                      const float* __restrict__ Wf,
                                                      unsigned short* __restrict__ h) {
  __shared__ float mst[GH_NODES * 36];   // padded stride 36 floats (9 float4)
  int bid = blockIdx.x;
  int r = bid % 7;                       // plane
  int n0 = (bid / 7) * GH_NODES;         // tile
  {
    const float4* x4 = (const float4*)(x + (size_t)n0 * 32);
    int t = threadIdx.x;                 // 1280 float4 in 2 rounds
    int row = t >> 3, col = t & 7;
    *(float4*)&mst[row * 36 + col * 4] = x4[t];
    if (t < 256) {
      int g = 1024 + t;
      *(float4*)&mst[(g >> 3) * 36 + (g & 7) * 4] = x4[g];
    }
  }
  int lane = threadIdx.x & 63, wv = threadIdx.x >> 6;
  int half = lane >> 5, l5 = lane & 31;
  const float* Wr = Wf + r * 1024;
  float w[32];
#pragma unroll
  for (int i = 0; i < 32; ++i) w[i] = Wr[i * 32 + l5];   // once; L2-hot broadcast
  __syncthreads();
  unsigned short* hr = h + (size_t)r * N_NODES * 32;
#pragma unroll
  for (int k = 0; k < 5; ++k) {
    int nl = wv * 10 + k * 2 + half;                      // 2 nodes per wave
    const float4* mrow = (const float4*)&mst[nl * 36];
    float a0 = 0.f, a1 = 0.f, a2 = 0.f, a3 = 0.f;         // 4 independent chains
#pragma unroll
    for (int i4 = 0; i4 < 8; i4 += 2) {
      float4 p = mrow[i4];                                // LDS broadcast read
      float4 q = mrow[i4 + 1];
      a0 = fmaf(p.x, w[4 * i4 + 0], a0);
      a0 = fmaf(p.y, w[4 * i4 + 1], a0);
      a1 = fmaf(p.z, w[4 * i4 + 2], a1);
      a1 = fmaf(p.w, w[4 * i4 + 3], a1);
      a2 = fmaf(q.x, w[4 * i4 + 4], a2);
      a2 = fmaf(q.y, w[4 * i4 + 5], a2);
      a3 = fmaf(q.z, w[4 * i4 + 6], a3);
      a3 = fmaf(q.w, w[4 * i4 + 7], a3);
    }
    float acc = (a0 + a1) + (a2 + a3);
    hr[(size_t)(n0 + nl) * 32 + l5] = f2bf(acc);          // coalesced 2B store
  }
}

// ------------- consume: bf16 gather-sum; 256-thr blocks; 2-chunk pipeline -----
// lane = q*16 + l4 (q=0..3): handles features {2*l4, 2*l4+1} of edge (e + q mod 4)
template <bool RELU>
__global__ __launch_bounds__(256) void consume_kernel(const unsigned short* __restrict__ h,
                                                      const int* __restrict__ offs,
                                                      const unsigned* __restrict__ eps,
                                                      const float* __restrict__ bias,
                                                      float* __restrict__ y) {
  int wv = threadIdx.x >> 6, lane = threadIdx.x & 63;
  int l5 = lane & 31;                    // eps slot
  int q = lane >> 4;                     // quarter 0..3 (edge sub-index)
  int l4 = lane & 15;                    // feature pair index
  int n = blockIdx.x * 4 + wv;           // grid exact: 25000*4 = 100000
  int b0 = offs[n * N_REL], b6 = offs[n * N_REL + 6];
  unsigned F4 = (unsigned)(l4 << 2);     // byte offset of feature pair in 64B row
  const char* hb = (const char*)h;
  float acc0 = 0.f, acc1 = 0.f;
#pragma unroll 2
  for (int chunk = b0; chunk < b6; chunk += 32) {
    int myp = chunk + l5;
    int cl = (myp < b6) ? myp : (b6 - 1);
    unsigned ep = eps[cl];               // one 4B coalesced load per 32 edges
    unsigned en = (ep >> 12) << 6;       // row byte offset (bf16 row = 64B)
    float sc = (myp < b6) ? 1.f / (float)(ep & 4095u) : 0.f;   // exact 1/cnt
#pragma unroll
    for (int e = 0; e < 32; e += 8) {
      // 2 gather instrs cover 8 edges (4 rows x 16 lanes each)
      unsigned q0 = __shfl(en, e + 0 + q, 32);      // my edge's row offset
      unsigned q1 = __shfl(en, e + 4 + q, 32);
      float s0 = __shfl(sc, e + 0 + q, 32);
      float s1 = __shfl(sc, e + 4 + q, 32);
      unsigned v0 = *(const unsigned*)(hb + (q0 | F4));   // 2 bf16 features
      unsigned v1 = *(const unsigned*)(hb + (q1 | F4));
      acc0 = fmaf(s0, __uint_as_float(v0 << 16), acc0);           // even feat
      acc1 = fmaf(s0, __uint_as_float(v0 & 0xffff0000u), acc1);   // odd feat
      acc0 = fmaf(s1, __uint_as_float(v1 << 16), acc0);
      acc1 = fmaf(s1, __uint_as_float(v1 & 0xffff0000u), acc1);
    }
  }
  // combine quarters (each quarter summed a different residue class of edges)
  acc0 += __shfl_xor(acc0, 16);
  acc0 += __shfl_xor(acc0, 32);
  acc1 += __shfl_xor(acc1, 16);
  acc1 += __shfl_xor(acc1, 32);
  // root row (bf16) + bias
  unsigned rv = *(const unsigned*)(hb + ((((size_t)6 * N_NODES + n) << 6)) + F4);
  float r0 = acc0 + __uint_as_float(rv << 16) + bias[2 * l4];
  float r1 = acc1 + __uint_as_float(rv & 0xffff0000u) + bias[2 * l4 + 1];
  if (RELU) { r0 = fmaxf(r0, 0.f); r1 = fmaxf(r1, 0.f); }
  if (lane < 16) {
    float2 st; st.x = r0; st.y = r1;
    *(float2*)(y + (size_t)n * 32 + 2 * l4) = st;
  }
}

extern "C" void kernel_launch(void* const* d_in, const int* in_sizes, int n_in,
                              void* d_out, int out_size, void* d_ws, size_t ws_size,
                              hipStream_t stream) {
  const float* embedding = (const float*)d_in[0];
  const int*   ei        = (const int*)d_in[1];     // [2, E]: src row, dst row
  const int*   et        = (const int*)d_in[2];
  const float* comp1  = (const float*)d_in[3];
  const float* basis1 = (const float*)d_in[4];
  const float* root1  = (const float*)d_in[5];
  const float* bias1  = (const float*)d_in[6];
  const float* comp2  = (const float*)d_in[7];
  const float* basis2 = (const float*)d_in[8];
  const float* root2  = (const float*)d_in[9];
  const float* bias2  = (const float*)d_in[10];
  float* out = (float*)d_out;

  const int* src = ei;
  const int* dst = ei + N_EDGES;

  float* ws = (float*)d_ws;
  size_t o = 0;
  float* Wf1 = ws + o; o += 7 * DIM * DIM;
  float* Wf2 = ws + o; o += 7 * DIM * DIM;
  float* x1  = ws + o; o += (size_t)N_NODES * DIM;
  unsigned short* h = (unsigned short*)(ws + o);
  o += (size_t)7 * N_NODES * DIM / 2 + 16;               // bf16 h: 44.8 MB
  int* offs       = (int*)(ws + o); o += N_SEG + 1;
  unsigned* eps   = (unsigned*)(ws + o); o += N_EDGES;   // packed row|cnt
  int* cnt2       = (int*)(ws + o); o += SCAN_N;
  int* bOffs      = (int*)(ws + o); o += CB + 1;
  unsigned* packed = (unsigned*)h;       // alias: dead before gemm_h writes h

  hist2_kernel<<<NBLK, 1024, 0, stream>>>(dst, cnt2);
  scan2_kernel<<<1, 1024, 0, stream>>>(cnt2, bOffs);
  scatter2_kernel<<<NBLK, 1024, 0, stream>>>(src, dst, et, cnt2, packed);
  phaseB_kernel<<<CB, 1024, 0, stream>>>(packed, bOffs, offs, eps);
  weights_kernel<<<(2 * 7 * DIM * DIM + 255) / 256, 256, 0, stream>>>(
      comp1, basis1, root1, comp2, basis2, root2, Wf1, Wf2);

  // layer 1
  gemm_h_kernel<<<7 * (N_NODES / GH_NODES), 1024, 0, stream>>>(embedding, Wf1, h);
  consume_kernel<true><<<N_NODES / 4, 256, 0, stream>>>(h, offs, eps, bias1, x1);
  // layer 2
  gemm_h_kernel<<<7 * (N_NODES / GH_NODES), 1024, 0, stream>>>(x1, Wf2, h);
  consume_kernel<false><<<N_NODES / 4, 256, 0, stream>>>(h, offs, eps, bias2, out);
}